// Round 4
// baseline (93.067 us; speedup 1.0000x reference)
//
#include <hip/hip_runtime.h>
#include <math.h>

#define BATCH 8
#define CH    512
#define NPIX  1024
#define NH    4

typedef __attribute__((ext_vector_type(8))) short bf16x8;
typedef __attribute__((ext_vector_type(4))) float f32x4;

// 1/sqrt(128) * log2(e): folded into Wq/bq so softmax = exp2(s - m)
#define QSC (0.088388347648318447f * 1.4426950408889634f)

__device__ inline unsigned short f2bf_rne(float f) {
    unsigned int u = __float_as_uint(f);
    return (unsigned short)((u + 0x7FFFu + ((u >> 16) & 1u)) >> 16);
}
__device__ inline unsigned int pack_bf2_trunc(float a, float b) {
    return (__float_as_uint(a) >> 16) | (__float_as_uint(b) & 0xFFFF0000u);
}

// ---------------------------------------------------------------------------
// Prep A: X [b][c][n] fp32 -> XT [b][n][c] bf16   (64x64 LDS tiles, pad 65)
// ---------------------------------------------------------------------------
__global__ __launch_bounds__(256) void x_transpose(
    const float* __restrict__ x, unsigned short* __restrict__ XT)
{
    __shared__ float S[64][65];
    const int t = threadIdx.x;
    const int a = t & 15, g = t >> 4;
    const int n0 = blockIdx.x * 64, c0 = blockIdx.y * 64, b = blockIdx.z;
    const float* xb = x + ((size_t)b * CH + c0) * NPIX + n0;
    #pragma unroll
    for (int i = 0; i < 4; ++i) {
        const int c = g + 16 * i;
        const float4 v = *(const float4*)&xb[(size_t)c * NPIX + 4 * a];
        S[c][4*a+0] = v.x; S[c][4*a+1] = v.y; S[c][4*a+2] = v.z; S[c][4*a+3] = v.w;
    }
    __syncthreads();
    unsigned short* ob = XT + ((size_t)b * NPIX + n0) * CH + c0;
    #pragma unroll
    for (int i = 0; i < 4; ++i) {
        const int n = g + 16 * i;
        unsigned short b0 = f2bf_rne(S[4*a+0][n]);
        unsigned short b1 = f2bf_rne(S[4*a+1][n]);
        unsigned short b2 = f2bf_rne(S[4*a+2][n]);
        unsigned short b3 = f2bf_rne(S[4*a+3][n]);
        uint2 st;
        st.x = (unsigned int)b0 | ((unsigned int)b1 << 16);
        st.y = (unsigned int)b2 | ((unsigned int)b3 << 16);
        *(uint2*)&ob[(size_t)n * CH + 4 * a] = st;
    }
}

// ---------------------------------------------------------------------------
// Prep B: W fp32 -> Wb [768][512] bf16; rows 0..128 = Wq * QSC, 128..256 = Wk,
// 256..768 = Wv.
// ---------------------------------------------------------------------------
__global__ __launch_bounds__(256) void w_convert(
    const float* __restrict__ Wq, const float* __restrict__ Wk,
    const float* __restrict__ Wv, unsigned short* __restrict__ Wb)
{
    const size_t idx = ((size_t)blockIdx.x * 256 + threadIdx.x) * 4;  // < 768*512
    float4 v;
    if (idx < 65536) {
        v = *(const float4*)&Wq[idx];
        v.x *= QSC; v.y *= QSC; v.z *= QSC; v.w *= QSC;
    } else if (idx < 131072) {
        v = *(const float4*)&Wk[idx - 65536];
    } else {
        v = *(const float4*)&Wv[idx - 131072];
    }
    uint2 st;
    st.x = (unsigned int)f2bf_rne(v.x) | ((unsigned int)f2bf_rne(v.y) << 16);
    st.y = (unsigned int)f2bf_rne(v.z) | ((unsigned int)f2bf_rne(v.w) << 16);
    *(uint2*)&Wb[idx] = st;
}

// ---------------------------------------------------------------------------
// QKV projection, MFMA, LDS-free mainloop (unchanged).
// ---------------------------------------------------------------------------
__global__ __launch_bounds__(256, 2) void qkv_proj(
    const unsigned short* __restrict__ XT, const unsigned short* __restrict__ Wb,
    const float* __restrict__ bq, const float* __restrict__ bk,
    const float* __restrict__ bv,
    unsigned short* __restrict__ QT, unsigned short* __restrict__ KT,
    unsigned short* __restrict__ V)
{
    __shared__ unsigned short OT[4][2048];   // per-wave 64n x 32o, 8B-granule swizzle
    const int t = threadIdx.x, w = t >> 6, l = t & 63;
    const int lo = l & 15, hi = l >> 4;
    const int b = blockIdx.z;
    const int o0 = blockIdx.y * 64 + (w >> 1) * 32;
    const int n0 = blockIdx.x * 128 + (w & 1) * 64;

    const unsigned short* Ab = Wb + (size_t)(o0 + lo) * CH + hi * 8;
    const unsigned short* Bb = XT + ((size_t)b * NPIX + n0 + lo) * CH + hi * 8;

    f32x4 acc[2][4] = {};
    #pragma unroll 4
    for (int k = 0; k < CH; k += 32) {
        bf16x8 af[2], bf[4];
        #pragma unroll
        for (int i = 0; i < 2; ++i) af[i] = *(const bf16x8*)(Ab + i * 8192 + k);
        #pragma unroll
        for (int j = 0; j < 4; ++j) bf[j] = *(const bf16x8*)(Bb + j * 8192 + k);
        #pragma unroll
        for (int i = 0; i < 2; ++i)
            #pragma unroll
            for (int j = 0; j < 4; ++j)
                acc[i][j] = __builtin_amdgcn_mfma_f32_16x16x32_bf16(af[i], bf[j], acc[i][j], 0, 0, 0);
    }

    float bias[2][4];
    #pragma unroll
    for (int i = 0; i < 2; ++i)
        #pragma unroll
        for (int r = 0; r < 4; ++r) {
            const int orow = o0 + i * 16 + hi * 4 + r;
            if (o0 < 128)      bias[i][r] = bq[orow] * QSC;
            else if (o0 < 256) bias[i][r] = bk[orow - 128];
            else               bias[i][r] = bv[orow - 256];
        }

    if (o0 < 256) {
        const bool isQ = (o0 < 128);
        const int hh = (o0 & 127) >> 5;
        #pragma unroll
        for (int i = 0; i < 2; ++i)
            #pragma unroll
            for (int j = 0; j < 4; ++j) {
                const int nl = j * 16 + lo;
                const int og = i * 4 + hi;
                unsigned short v0 = f2bf_rne(acc[i][j][0] + bias[i][0]);
                unsigned short v1 = f2bf_rne(acc[i][j][1] + bias[i][1]);
                unsigned short v2 = f2bf_rne(acc[i][j][2] + bias[i][2]);
                unsigned short v3 = f2bf_rne(acc[i][j][3] + bias[i][3]);
                uint2 st;
                st.x = (unsigned int)v0 | ((unsigned int)v1 << 16);
                st.y = (unsigned int)v2 | ((unsigned int)v3 << 16);
                *(uint2*)&OT[w][nl * 32 + ((og ^ (nl & 7)) << 2)] = st;
            }
        unsigned short* outp = (isQ ? QT : KT) + (size_t)(b * NH + hh) * NPIX * 32;
        #pragma unroll
        for (int it = 0; it < 4; ++it) {
            const int nl = (l >> 2) + 16 * it, seg = l & 3;
            const int g0 = (2 * seg) ^ (nl & 7);
            const int g1 = (2 * seg + 1) ^ (nl & 7);
            const uint2 p0 = *(uint2*)&OT[w][nl * 32 + g0 * 4];
            const uint2 p1 = *(uint2*)&OT[w][nl * 32 + g1 * 4];
            uint4 st; st.x = p0.x; st.y = p0.y; st.z = p1.x; st.w = p1.y;
            *(uint4*)&outp[(size_t)(n0 + nl) * 32 + seg * 8] = st;
        }
    } else {
        const int hh = (o0 - 256) >> 7;
        const int cb = (o0 - 256) & 127;
        unsigned short* vb = V + (size_t)(b * NH + hh) * 128 * NPIX;
        #pragma unroll
        for (int i = 0; i < 2; ++i)
            #pragma unroll
            for (int j = 0; j < 4; ++j)
                #pragma unroll
                for (int r = 0; r < 4; ++r) {
                    const int c = cb + i * 16 + hi * 4 + r;
                    const int n = n0 + j * 16 + lo;
                    vb[(size_t)c * NPIX + n] = f2bf_rne(acc[i][j][r] + bias[i][r]);
                }
    }
}

// ---------------------------------------------------------------------------
// Fused flash attention v4: channel-split wave pairs.
// Block = 4 waves: wave (wr, chalf) with wr = w>>1 (two 32-row groups),
// chalf = w&1 (64 of 128 V-channels). QK^T+softmax duplicated per chalf;
// vf/of halved so the kf+vf double-buffered prefetch fits in registers.
// Grid 512 blocks -> 2 waves/SIMD TLP. XCD-grouped bh decode keeps K/V
// L2-resident. No barriers.
// ---------------------------------------------------------------------------
__global__ __launch_bounds__(256, 2) void attn(
    const unsigned short* __restrict__ QT, const unsigned short* __restrict__ KT,
    const unsigned short* __restrict__ V,  const float* __restrict__ x,
    const float* __restrict__ gamma, float* __restrict__ out)
{
    __shared__ float SM[4][2176];   // per wave: Ps dbuf 2x4KB bf16  /  Ot 64*33 f
    const int t = threadIdx.x, w = t >> 6, l = t & 63;
    const int lo = l & 15, hi = l >> 4;

    // XCD-grouped decode: u%8 = XCD = bh%8 (4 bh per XCD, ~1.5 MB working set)
    const int u = blockIdx.x;              // 0..511
    const int xcd = u & 7;
    const int rr = u >> 3;                 // 0..63
    const int nt = rr & 15;                // 16 n-tiles of 64 rows
    const int bh = xcd | ((rr >> 4) << 3); // 0..31
    const int wr = w >> 1;                 // 32-row group within n-tile
    const int chalf = w & 1;               // which 64 of the 128 channels
    const int n0w = nt * 64 + wr * 32;

    unsigned short* Ps = (unsigned short*)&SM[w][0];
    float* Ot = &SM[w][0];

    const unsigned short* Qb = QT + (size_t)bh * NPIX * 32;
    const unsigned short* Kb = KT + (size_t)bh * NPIX * 32;
    const unsigned short* Vb = V + ((size_t)bh * 128 + chalf * 64) * NPIX;

    bf16x8 qf[2];
    #pragma unroll
    for (int j = 0; j < 2; ++j)
        qf[j] = *(const bf16x8*)&Qb[(size_t)(n0w + j * 16 + lo) * 32 + hi * 8];

    f32x4 of[2][4] = {};
    float mrow[2] = {-INFINITY, -INFINITY};
    float lrow[2] = {0.f, 0.f};

    bf16x8 kf[2][4], vf[2][4][2];
    // prologue: tile 0
    #pragma unroll
    for (int i = 0; i < 4; ++i)
        kf[0][i] = *(const bf16x8*)&Kb[(size_t)(i * 16 + lo) * 32 + hi * 8];
    #pragma unroll
    for (int c = 0; c < 4; ++c)
        #pragma unroll
        for (int ks = 0; ks < 2; ++ks)
            vf[0][c][ks] = *(const bf16x8*)&Vb[(size_t)(c * 16 + lo) * NPIX + ks * 32 + hi * 8];

    #pragma unroll 2
    for (int tix = 0; tix < 16; ++tix) {
        const int cur = tix & 1, nx = cur ^ 1;
        const int mN = ((tix + 1) & 15) * 64;   // next tile (wraps harmlessly)

        // ---- prefetch next tile's K/V fragments (latency hides under compute)
        #pragma unroll
        for (int i = 0; i < 4; ++i)
            kf[nx][i] = *(const bf16x8*)&Kb[(size_t)(mN + i * 16 + lo) * 32 + hi * 8];
        #pragma unroll
        for (int c = 0; c < 4; ++c)
            #pragma unroll
            for (int ks = 0; ks < 2; ++ks)
                vf[nx][c][ks] = *(const bf16x8*)&Vb[(size_t)(c * 16 + lo) * NPIX + mN + ks * 32 + hi * 8];

        // ---- S^T = mfma(K, Q): D[col=n (lo), rowgrp=m (hi*4+r)]
        const f32x4 zero = {0.f, 0.f, 0.f, 0.f};
        f32x4 sf[4][2];
        #pragma unroll
        for (int i = 0; i < 4; ++i)
            #pragma unroll
            for (int j = 0; j < 2; ++j)
                sf[i][j] = __builtin_amdgcn_mfma_f32_16x16x32_bf16(kf[cur][i], qf[j], zero, 0, 0, 0);

        unsigned short* Pb = Ps + cur * 2048;   // bf16 units; 4KB halves

        float fsc[2]; bool grow[2];
        #pragma unroll
        for (int j = 0; j < 2; ++j) {
            float mx = fmaxf(fmaxf(sf[0][j][0], sf[0][j][1]), fmaxf(sf[0][j][2], sf[0][j][3]));
            #pragma unroll
            for (int i = 1; i < 4; ++i) {
                const float m2 = fmaxf(fmaxf(sf[i][j][0], sf[i][j][1]), fmaxf(sf[i][j][2], sf[i][j][3]));
                mx = fmaxf(mx, m2);
            }
            mx = fmaxf(mx, __shfl_xor(mx, 16));
            mx = fmaxf(mx, __shfl_xor(mx, 32));
            grow[j] = __any(mx > mrow[j]) != 0;
            fsc[j] = 1.f;
            if (grow[j]) {
                const float mn2 = fmaxf(mrow[j], mx);
                fsc[j] = __builtin_amdgcn_exp2f(mrow[j] - mn2);
                mrow[j] = mn2;
            }
            const float mj = mrow[j];
            const int nl = j * 16 + lo;
            float ps = 0.f;
            #pragma unroll
            for (int i = 0; i < 4; ++i) {
                const float p0 = __builtin_amdgcn_exp2f(sf[i][j][0] - mj);
                const float p1 = __builtin_amdgcn_exp2f(sf[i][j][1] - mj);
                const float p2 = __builtin_amdgcn_exp2f(sf[i][j][2] - mj);
                const float p3 = __builtin_amdgcn_exp2f(sf[i][j][3] - mj);
                ps += (p0 + p1) + (p2 + p3);
                const int mchunk = i * 2 + (hi >> 1);
                const int off = nl * 64 + ((mchunk ^ (nl & 7)) << 3) + ((hi & 1) << 2);
                uint2 st; st.x = pack_bf2_trunc(p0, p1); st.y = pack_bf2_trunc(p2, p3);
                *(uint2*)&Pb[off] = st;
            }
            ps += __shfl_xor(ps, 16);
            ps += __shfl_xor(ps, 32);
            lrow[j] = lrow[j] * fsc[j] + ps;
        }

        // ---- PV per inf (rows inf*16+lo were written by j==inf above)
        #pragma unroll
        for (int inf = 0; inf < 2; ++inf) {
            const int nl = inf * 16 + lo;
            bf16x8 pa[2];
            #pragma unroll
            for (int ks = 0; ks < 2; ++ks)
                pa[ks] = *(const bf16x8*)&Pb[nl * 64 + (((ks * 4 + hi) ^ (nl & 7)) << 3)];
            if (grow[inf]) {
                #pragma unroll
                for (int r = 0; r < 4; ++r) {
                    const float f = __shfl(fsc[inf], hi * 4 + r, 16);
                    #pragma unroll
                    for (int c = 0; c < 4; ++c) of[inf][c][r] *= f;
                }
            }
            #pragma unroll
            for (int c = 0; c < 4; ++c) {
                of[inf][c] = __builtin_amdgcn_mfma_f32_16x16x32_bf16(pa[0], vf[cur][c][0], of[inf][c], 0, 0, 0);
                of[inf][c] = __builtin_amdgcn_mfma_f32_16x16x32_bf16(pa[1], vf[cur][c][1], of[inf][c], 0, 0, 0);
            }
        }
    }

    // ---- epilogue: normalize, transpose via LDS, coalesced gamma*o + x
    float invv[2][4];
    #pragma unroll
    for (int inf = 0; inf < 2; ++inf)
        #pragma unroll
        for (int r = 0; r < 4; ++r)
            invv[inf][r] = 1.0f / __shfl(lrow[inf], hi * 4 + r, 16);

    const float g = gamma[0];
    const int b = bh >> 2, h = bh & 3;

    #pragma unroll
    for (int inf = 0; inf < 2; ++inf)
        #pragma unroll
        for (int r = 0; r < 4; ++r) {
            const int n = inf * 16 + hi * 4 + r;
            #pragma unroll
            for (int cf = 0; cf < 4; ++cf)
                Ot[(cf * 16 + lo) * 33 + n] = of[inf][cf][r] * invv[inf][r];
        }
    const size_t cbase = (size_t)b * CH + h * 128 + chalf * 64;
    #pragma unroll 4
    for (int cc = 0; cc < 32; ++cc) {
        const int cl = (l >> 5) + 2 * cc;
        const int n = l & 31;
        const float o = Ot[cl * 33 + n];
        const size_t gi = (cbase + cl) * NPIX + n0w + n;
        out[gi] = fmaf(g, o, x[gi]);
    }
}

// ---------------------------------------------------------------------------
extern "C" void kernel_launch(void* const* d_in, const int* in_sizes, int n_in,
                              void* d_out, int out_size, void* d_ws, size_t ws_size,
                              hipStream_t stream)
{
    const float* x     = (const float*)d_in[0];
    const float* Wq    = (const float*)d_in[1];
    const float* bq    = (const float*)d_in[2];
    const float* Wk    = (const float*)d_in[3];
    const float* bk    = (const float*)d_in[4];
    const float* Wv    = (const float*)d_in[5];
    const float* bv    = (const float*)d_in[6];
    const float* gamma = (const float*)d_in[7];
    float* out = (float*)d_out;

    char* ws = (char*)d_ws;
    unsigned short* XTp = (unsigned short*)(ws);             // 8 MB
    unsigned short* Wbp = (unsigned short*)(ws + 8388608);   // 768 KB
    unsigned short* QTp = (unsigned short*)(ws + 9175040);   // 2 MB
    unsigned short* KTp = (unsigned short*)(ws + 11272192);  // 2 MB
    unsigned short* Vp  = (unsigned short*)(ws + 13369344);  // 8 MB

    x_transpose<<<dim3(16, 8, 8), 256, 0, stream>>>(x, XTp);
    w_convert<<<dim3(384), 256, 0, stream>>>(Wq, Wk, Wv, Wbp);
    qkv_proj<<<dim3(8, 12, 8), 256, 0, stream>>>(XTp, Wbp, bq, bk, bv, QTp, KTp, Vp);
    attn<<<dim3(512), 256, 0, stream>>>(QTp, KTp, Vp, x, gamma, out);
}

// Round 5
// 89.980 us; speedup vs baseline: 1.0343x; 1.0343x over previous
//
#include <hip/hip_runtime.h>
#include <math.h>

#define BATCH 8
#define CH    512
#define NPIX  1024
#define NH    4

typedef __attribute__((ext_vector_type(8))) short bf16x8;
typedef __attribute__((ext_vector_type(4))) float f32x4;

// 1/sqrt(128) * log2(e): folded into Wq/bq so softmax = exp2(s - m)
#define QSC (0.088388347648318447f * 1.4426950408889634f)

__device__ inline unsigned short f2bf_rne(float f) {
    unsigned int u = __float_as_uint(f);
    return (unsigned short)((u + 0x7FFFu + ((u >> 16) & 1u)) >> 16);
}
__device__ inline unsigned int pack_bf2_trunc(float a, float b) {
    return (__float_as_uint(a) >> 16) | (__float_as_uint(b) & 0xFFFF0000u);
}

// ---------------------------------------------------------------------------
// Prep (fused): z<8 -> X [b][c][n] fp32 -> XT [b][n][c] bf16 (64x64 tiles);
//               z==8 -> W fp32 -> Wb [768][512] bf16 (Wq rows pre-scaled).
// ---------------------------------------------------------------------------
__global__ __launch_bounds__(256) void prep(
    const float* __restrict__ x,
    const float* __restrict__ Wq, const float* __restrict__ Wk,
    const float* __restrict__ Wv,
    unsigned short* __restrict__ XT, unsigned short* __restrict__ Wb)
{
    if (blockIdx.z == 8) {
        const int gid = blockIdx.y * 16 + blockIdx.x;   // 0..127
        #pragma unroll
        for (int rep = 0; rep < 3; ++rep) {
            const size_t idx = ((size_t)(rep * 128 + gid) * 256 + threadIdx.x) * 4;
            float4 v;
            if (idx < 65536) {
                v = *(const float4*)&Wq[idx];
                v.x *= QSC; v.y *= QSC; v.z *= QSC; v.w *= QSC;
            } else if (idx < 131072) {
                v = *(const float4*)&Wk[idx - 65536];
            } else {
                v = *(const float4*)&Wv[idx - 131072];
            }
            uint2 st;
            st.x = (unsigned int)f2bf_rne(v.x) | ((unsigned int)f2bf_rne(v.y) << 16);
            st.y = (unsigned int)f2bf_rne(v.z) | ((unsigned int)f2bf_rne(v.w) << 16);
            *(uint2*)&Wb[idx] = st;
        }
        return;
    }
    __shared__ float S[64][65];
    const int t = threadIdx.x;
    const int a = t & 15, g = t >> 4;
    const int n0 = blockIdx.x * 64, c0 = blockIdx.y * 64, b = blockIdx.z;
    const float* xb = x + ((size_t)b * CH + c0) * NPIX + n0;
    #pragma unroll
    for (int i = 0; i < 4; ++i) {
        const int c = g + 16 * i;
        const float4 v = *(const float4*)&xb[(size_t)c * NPIX + 4 * a];
        S[c][4*a+0] = v.x; S[c][4*a+1] = v.y; S[c][4*a+2] = v.z; S[c][4*a+3] = v.w;
    }
    __syncthreads();
    unsigned short* ob = XT + ((size_t)b * NPIX + n0) * CH + c0;
    #pragma unroll
    for (int i = 0; i < 4; ++i) {
        const int n = g + 16 * i;
        unsigned short b0 = f2bf_rne(S[4*a+0][n]);
        unsigned short b1 = f2bf_rne(S[4*a+1][n]);
        unsigned short b2 = f2bf_rne(S[4*a+2][n]);
        unsigned short b3 = f2bf_rne(S[4*a+3][n]);
        uint2 st;
        st.x = (unsigned int)b0 | ((unsigned int)b1 << 16);
        st.y = (unsigned int)b2 | ((unsigned int)b3 << 16);
        *(uint2*)&ob[(size_t)n * CH + 4 * a] = st;
    }
}

// ---------------------------------------------------------------------------
// QKV projection, MFMA, LDS-free mainloop (unchanged).
// ---------------------------------------------------------------------------
__global__ __launch_bounds__(256, 2) void qkv_proj(
    const unsigned short* __restrict__ XT, const unsigned short* __restrict__ Wb,
    const float* __restrict__ bq, const float* __restrict__ bk,
    const float* __restrict__ bv,
    unsigned short* __restrict__ QT, unsigned short* __restrict__ KT,
    unsigned short* __restrict__ V)
{
    __shared__ unsigned short OT[4][2048];
    const int t = threadIdx.x, w = t >> 6, l = t & 63;
    const int lo = l & 15, hi = l >> 4;
    const int b = blockIdx.z;
    const int o0 = blockIdx.y * 64 + (w >> 1) * 32;
    const int n0 = blockIdx.x * 128 + (w & 1) * 64;

    const unsigned short* Ab = Wb + (size_t)(o0 + lo) * CH + hi * 8;
    const unsigned short* Bb = XT + ((size_t)b * NPIX + n0 + lo) * CH + hi * 8;

    f32x4 acc[2][4] = {};
    #pragma unroll 4
    for (int k = 0; k < CH; k += 32) {
        bf16x8 af[2], bf[4];
        #pragma unroll
        for (int i = 0; i < 2; ++i) af[i] = *(const bf16x8*)(Ab + i * 8192 + k);
        #pragma unroll
        for (int j = 0; j < 4; ++j) bf[j] = *(const bf16x8*)(Bb + j * 8192 + k);
        #pragma unroll
        for (int i = 0; i < 2; ++i)
            #pragma unroll
            for (int j = 0; j < 4; ++j)
                acc[i][j] = __builtin_amdgcn_mfma_f32_16x16x32_bf16(af[i], bf[j], acc[i][j], 0, 0, 0);
    }

    float bias[2][4];
    #pragma unroll
    for (int i = 0; i < 2; ++i)
        #pragma unroll
        for (int r = 0; r < 4; ++r) {
            const int orow = o0 + i * 16 + hi * 4 + r;
            if (o0 < 128)      bias[i][r] = bq[orow] * QSC;
            else if (o0 < 256) bias[i][r] = bk[orow - 128];
            else               bias[i][r] = bv[orow - 256];
        }

    if (o0 < 256) {
        const bool isQ = (o0 < 128);
        const int hh = (o0 & 127) >> 5;
        #pragma unroll
        for (int i = 0; i < 2; ++i)
            #pragma unroll
            for (int j = 0; j < 4; ++j) {
                const int nl = j * 16 + lo;
                const int og = i * 4 + hi;
                unsigned short v0 = f2bf_rne(acc[i][j][0] + bias[i][0]);
                unsigned short v1 = f2bf_rne(acc[i][j][1] + bias[i][1]);
                unsigned short v2 = f2bf_rne(acc[i][j][2] + bias[i][2]);
                unsigned short v3 = f2bf_rne(acc[i][j][3] + bias[i][3]);
                uint2 st;
                st.x = (unsigned int)v0 | ((unsigned int)v1 << 16);
                st.y = (unsigned int)v2 | ((unsigned int)v3 << 16);
                *(uint2*)&OT[w][nl * 32 + ((og ^ (nl & 7)) << 2)] = st;
            }
        unsigned short* outp = (isQ ? QT : KT) + (size_t)(b * NH + hh) * NPIX * 32;
        #pragma unroll
        for (int it = 0; it < 4; ++it) {
            const int nl = (l >> 2) + 16 * it, seg = l & 3;
            const int g0 = (2 * seg) ^ (nl & 7);
            const int g1 = (2 * seg + 1) ^ (nl & 7);
            const uint2 p0 = *(uint2*)&OT[w][nl * 32 + g0 * 4];
            const uint2 p1 = *(uint2*)&OT[w][nl * 32 + g1 * 4];
            uint4 st; st.x = p0.x; st.y = p0.y; st.z = p1.x; st.w = p1.y;
            *(uint4*)&outp[(size_t)(n0 + nl) * 32 + seg * 8] = st;
        }
    } else {
        const int hh = (o0 - 256) >> 7;
        const int cb = (o0 - 256) & 127;
        unsigned short* vb = V + (size_t)(b * NH + hh) * 128 * NPIX;
        #pragma unroll
        for (int i = 0; i < 2; ++i)
            #pragma unroll
            for (int j = 0; j < 4; ++j)
                #pragma unroll
                for (int r = 0; r < 4; ++r) {
                    const int c = cb + i * 16 + hi * 4 + r;
                    const int n = n0 + j * 16 + lo;
                    vb[(size_t)c * NPIX + n] = f2bf_rne(acc[i][j][r] + bias[i][r]);
                }
    }
}

// ---------------------------------------------------------------------------
// Fused flash attention v5: split-K wave quads.
// Block = 4 waves (kv = KV-half, ch = channel-half), 32 q-rows per block.
// Each wave: 8 KV tiles of 64, loads fenced with sched_barrier so the
// scheduler cannot sink them (compiler-proof prefetch). Partials merged
// through LDS (3 barriers), cooperative coalesced epilogue.
// Grid 1024 blocks, launch_bounds(256,3) -> 3 waves/SIMD.
// ---------------------------------------------------------------------------
__global__ __launch_bounds__(256, 3) void attn(
    const unsigned short* __restrict__ QT, const unsigned short* __restrict__ KT,
    const unsigned short* __restrict__ V,  const float* __restrict__ x,
    const float* __restrict__ gamma, float* __restrict__ out)
{
    __shared__ unsigned short PsAll[4][2048];   // 16 KB: per-wave P tile
    __shared__ float Xch[4608];                 // 18 KB: of-exchange / m,l / Ot

    const int t = threadIdx.x, w = t >> 6, l = t & 63;
    const int lo = l & 15, hi = l >> 4;
    const int kv = w >> 1, ch = w & 1;

    // XCD-grouped decode: u%8 = bh%8 -> per-XCD K/V working set ~1.5 MB (L2)
    const int u = blockIdx.x;              // 0..1023
    const int xcd = u & 7;
    const int rr = u >> 3;                 // 0..127
    const int nt = rr & 15;
    const int wr = (rr >> 4) & 1;
    const int q4 = rr >> 5;                // 0..3
    const int bh = xcd | (q4 << 3);
    const int n0b = nt * 64 + wr * 32;     // block's 32 q-rows

    unsigned short* Ps = PsAll[w];

    const unsigned short* Qb = QT + (size_t)bh * NPIX * 32;
    const unsigned short* Kb = KT + (size_t)bh * NPIX * 32;
    const unsigned short* Vb = V + ((size_t)bh * 128 + ch * 64) * NPIX;

    bf16x8 qf[2];
    #pragma unroll
    for (int j = 0; j < 2; ++j)
        qf[j] = *(const bf16x8*)&Qb[(size_t)(n0b + j * 16 + lo) * 32 + hi * 8];

    f32x4 of[2][4] = {};
    float mrow[2] = {-INFINITY, -INFINITY};
    float lrow[2] = {0.f, 0.f};

    for (int tix = 0; tix < 8; ++tix) {
        const int m0 = kv * 512 + tix * 64;

        // ---- tile loads (K frags + V frags), fenced so they can't be sunk
        bf16x8 kf[4], vf[4][2];
        #pragma unroll
        for (int i = 0; i < 4; ++i)
            kf[i] = *(const bf16x8*)&Kb[(size_t)(m0 + i * 16 + lo) * 32 + hi * 8];
        #pragma unroll
        for (int c = 0; c < 4; ++c)
            #pragma unroll
            for (int ks = 0; ks < 2; ++ks)
                vf[c][ks] = *(const bf16x8*)&Vb[(size_t)(c * 16 + lo) * NPIX + m0 + ks * 32 + hi * 8];
        __builtin_amdgcn_sched_barrier(0);

        // ---- S^T = mfma(K, Q): D[col=n (lo), rowgrp=m (hi*4+r)]
        const f32x4 zero = {0.f, 0.f, 0.f, 0.f};
        f32x4 sf[4][2];
        __builtin_amdgcn_s_setprio(1);
        #pragma unroll
        for (int i = 0; i < 4; ++i)
            #pragma unroll
            for (int j = 0; j < 2; ++j)
                sf[i][j] = __builtin_amdgcn_mfma_f32_16x16x32_bf16(kf[i], qf[j], zero, 0, 0, 0);
        __builtin_amdgcn_s_setprio(0);

        float fsc[2]; bool grow[2];
        #pragma unroll
        for (int j = 0; j < 2; ++j) {
            float mx = fmaxf(fmaxf(sf[0][j][0], sf[0][j][1]), fmaxf(sf[0][j][2], sf[0][j][3]));
            #pragma unroll
            for (int i = 1; i < 4; ++i) {
                const float m2 = fmaxf(fmaxf(sf[i][j][0], sf[i][j][1]), fmaxf(sf[i][j][2], sf[i][j][3]));
                mx = fmaxf(mx, m2);
            }
            mx = fmaxf(mx, __shfl_xor(mx, 16));
            mx = fmaxf(mx, __shfl_xor(mx, 32));
            grow[j] = __any(mx > mrow[j]) != 0;
            fsc[j] = 1.f;
            if (grow[j]) {
                const float mn2 = fmaxf(mrow[j], mx);
                fsc[j] = __builtin_amdgcn_exp2f(mrow[j] - mn2);
                mrow[j] = mn2;
            }
            const float mj = mrow[j];
            const int nl = j * 16 + lo;
            float ps = 0.f;
            #pragma unroll
            for (int i = 0; i < 4; ++i) {
                const float p0 = __builtin_amdgcn_exp2f(sf[i][j][0] - mj);
                const float p1 = __builtin_amdgcn_exp2f(sf[i][j][1] - mj);
                const float p2 = __builtin_amdgcn_exp2f(sf[i][j][2] - mj);
                const float p3 = __builtin_amdgcn_exp2f(sf[i][j][3] - mj);
                ps += (p0 + p1) + (p2 + p3);
                const int mchunk = i * 2 + (hi >> 1);
                const int off = nl * 64 + ((mchunk ^ (nl & 7)) << 3) + ((hi & 1) << 2);
                uint2 st; st.x = pack_bf2_trunc(p0, p1); st.y = pack_bf2_trunc(p2, p3);
                *(uint2*)&Ps[off] = st;
            }
            ps += __shfl_xor(ps, 16);
            ps += __shfl_xor(ps, 32);
            lrow[j] = lrow[j] * fsc[j] + ps;
        }

        // ---- PV per inf
        #pragma unroll
        for (int inf = 0; inf < 2; ++inf) {
            const int nl = inf * 16 + lo;
            bf16x8 pa[2];
            #pragma unroll
            for (int ks = 0; ks < 2; ++ks)
                pa[ks] = *(const bf16x8*)&Ps[nl * 64 + (((ks * 4 + hi) ^ (nl & 7)) << 3)];
            if (grow[inf]) {
                #pragma unroll
                for (int r = 0; r < 4; ++r) {
                    const float f = __shfl(fsc[inf], hi * 4 + r, 16);
                    #pragma unroll
                    for (int c = 0; c < 4; ++c) of[inf][c][r] *= f;
                }
            }
            __builtin_amdgcn_s_setprio(1);
            #pragma unroll
            for (int c = 0; c < 4; ++c) {
                of[inf][c] = __builtin_amdgcn_mfma_f32_16x16x32_bf16(pa[0], vf[c][0], of[inf][c], 0, 0, 0);
                of[inf][c] = __builtin_amdgcn_mfma_f32_16x16x32_bf16(pa[1], vf[c][1], of[inf][c], 0, 0, 0);
            }
            __builtin_amdgcn_s_setprio(0);
        }
    }

    // ---- merge partials: donors (kv=1) export of; everyone exports m,l
    if (kv == 1) {
        #pragma unroll
        for (int inf = 0; inf < 2; ++inf)
            #pragma unroll
            for (int cf = 0; cf < 4; ++cf)
                #pragma unroll
                for (int r = 0; r < 4; ++r)
                    Xch[ch * 1024 + (inf * 16 + hi * 4 + r) * 32 + cf * 8 + (lo & 7)
                        + ((lo >> 3) * 2048)] = of[inf][cf][r];
        // note: layout [lo>=8 half][ch][n][cf*8 + lo&7] keeps idx < 4096
    }
    if (hi == 0) {
        #pragma unroll
        for (int j = 0; j < 2; ++j) {
            Xch[4096 + (kv * 2 + ch) * 64 + j * 16 + lo] = mrow[j];
            Xch[4352 + (kv * 2 + ch) * 64 + j * 16 + lo] = lrow[j];
        }
    }
    __syncthreads();

    const float g = gamma[0];
    const int b = bh >> 2, h = bh & 3;

    if (kv == 0) {
        // combine with donor partials, normalize (still in regs)
        float inv[2][4], fA[2][4], fB[2][4];
        #pragma unroll
        for (int inf = 0; inf < 2; ++inf)
            #pragma unroll
            for (int r = 0; r < 4; ++r) {
                const int n = inf * 16 + hi * 4 + r;
                const float mA = Xch[4096 + ch * 64 + n];
                const float lA = Xch[4352 + ch * 64 + n];
                const float mB = Xch[4096 + (2 + ch) * 64 + n];
                const float lB = Xch[4352 + (2 + ch) * 64 + n];
                const float ms = fmaxf(mA, mB);
                const float a = __builtin_amdgcn_exp2f(mA - ms);
                const float bb = __builtin_amdgcn_exp2f(mB - ms);
                fA[inf][r] = a; fB[inf][r] = bb;
                inv[inf][r] = 1.0f / (lA * a + lB * bb);
            }
        f32x4 oc[2][4];
        #pragma unroll
        for (int inf = 0; inf < 2; ++inf)
            #pragma unroll
            for (int cf = 0; cf < 4; ++cf)
                #pragma unroll
                for (int r = 0; r < 4; ++r) {
                    const int n = inf * 16 + hi * 4 + r;
                    const float dn = Xch[ch * 1024 + n * 32 + cf * 8 + (lo & 7)
                                         + ((lo >> 3) * 2048)];
                    oc[inf][cf][r] = (of[inf][cf][r] * fA[inf][r] + dn * fB[inf][r]) * inv[inf][r];
                }
        __syncthreads();   // all combine reads done before Ot overwrites
        #pragma unroll
        for (int inf = 0; inf < 2; ++inf)
            #pragma unroll
            for (int cf = 0; cf < 4; ++cf)
                #pragma unroll
                for (int r = 0; r < 4; ++r)
                    Xch[(ch * 64 + cf * 16 + lo) * 33 + inf * 16 + hi * 4 + r] = oc[inf][cf][r];
    } else {
        __syncthreads();
    }
    __syncthreads();

    // cooperative epilogue: out = gamma*o + x, 32 c-rows per wave, coalesced
    {
        const size_t cbase = (size_t)b * CH + h * 128 + w * 32;
        #pragma unroll 4
        for (int cc = 0; cc < 16; ++cc) {
            const int c = cc * 2 + (l >> 5);
            const int n = l & 31;
            const float o = Xch[(w * 32 + c) * 33 + n];
            const size_t gi = (cbase + c) * NPIX + n0b + n;
            out[gi] = fmaf(g, o, x[gi]);
        }
    }
}

// ---------------------------------------------------------------------------
extern "C" void kernel_launch(void* const* d_in, const int* in_sizes, int n_in,
                              void* d_out, int out_size, void* d_ws, size_t ws_size,
                              hipStream_t stream)
{
    const float* x     = (const float*)d_in[0];
    const float* Wq    = (const float*)d_in[1];
    const float* bq    = (const float*)d_in[2];
    const float* Wk    = (const float*)d_in[3];
    const float* bk    = (const float*)d_in[4];
    const float* Wv    = (const float*)d_in[5];
    const float* bv    = (const float*)d_in[6];
    const float* gamma = (const float*)d_in[7];
    float* out = (float*)d_out;

    char* ws = (char*)d_ws;
    unsigned short* XTp = (unsigned short*)(ws);             // 8 MB
    unsigned short* Wbp = (unsigned short*)(ws + 8388608);   // 768 KB
    unsigned short* QTp = (unsigned short*)(ws + 9175040);   // 2 MB
    unsigned short* KTp = (unsigned short*)(ws + 11272192);  // 2 MB
    unsigned short* Vp  = (unsigned short*)(ws + 13369344);  // 8 MB

    prep<<<dim3(16, 8, 9), 256, 0, stream>>>(x, Wq, Wk, Wv, XTp, Wbp);
    qkv_proj<<<dim3(8, 12, 8), 256, 0, stream>>>(XTp, Wbp, bq, bk, bv, QTp, KTp, Vp);
    attn<<<dim3(1024), 256, 0, stream>>>(QTp, KTp, Vp, x, gamma, out);
}

// Round 6
// 89.076 us; speedup vs baseline: 1.0448x; 1.0102x over previous
//
#include <hip/hip_runtime.h>
#include <math.h>

#define BATCH 8
#define CH    512
#define NPIX  1024
#define NH    4

typedef __attribute__((ext_vector_type(8))) short bf16x8;
typedef __attribute__((ext_vector_type(4))) float f32x4;
typedef __attribute__((ext_vector_type(16))) float f32x16;
typedef __attribute__((ext_vector_type(4))) unsigned int u32x4;

// 1/sqrt(128) * log2(e): folded into Wq/bq so softmax = exp2(s - m)
#define QSC (0.088388347648318447f * 1.4426950408889634f)

__device__ inline unsigned short f2bf_rne(float f) {
    unsigned int u = __float_as_uint(f);
    return (unsigned short)((u + 0x7FFFu + ((u >> 16) & 1u)) >> 16);
}
__device__ inline unsigned int pack_bf2_trunc(float a, float b) {
    return (__float_as_uint(a) >> 16) | (__float_as_uint(b) & 0xFFFF0000u);
}

// ---------------------------------------------------------------------------
// Prep (fused): z<8 -> X [b][c][n] fp32 -> XT [b][n][c] bf16 (64x64 tiles);
//               z==8 -> W fp32 -> Wb [768][512] bf16 (Wq rows pre-scaled).
// ---------------------------------------------------------------------------
__global__ __launch_bounds__(256) void prep(
    const float* __restrict__ x,
    const float* __restrict__ Wq, const float* __restrict__ Wk,
    const float* __restrict__ Wv,
    unsigned short* __restrict__ XT, unsigned short* __restrict__ Wb)
{
    if (blockIdx.z == 8) {
        const int gid = blockIdx.y * 16 + blockIdx.x;   // 0..127
        #pragma unroll
        for (int rep = 0; rep < 3; ++rep) {
            const size_t idx = ((size_t)(rep * 128 + gid) * 256 + threadIdx.x) * 4;
            float4 v;
            if (idx < 65536) {
                v = *(const float4*)&Wq[idx];
                v.x *= QSC; v.y *= QSC; v.z *= QSC; v.w *= QSC;
            } else if (idx < 131072) {
                v = *(const float4*)&Wk[idx - 65536];
            } else {
                v = *(const float4*)&Wv[idx - 131072];
            }
            uint2 st;
            st.x = (unsigned int)f2bf_rne(v.x) | ((unsigned int)f2bf_rne(v.y) << 16);
            st.y = (unsigned int)f2bf_rne(v.z) | ((unsigned int)f2bf_rne(v.w) << 16);
            *(uint2*)&Wb[idx] = st;
        }
        return;
    }
    __shared__ float S[64][65];
    const int t = threadIdx.x;
    const int a = t & 15, g = t >> 4;
    const int n0 = blockIdx.x * 64, c0 = blockIdx.y * 64, b = blockIdx.z;
    const float* xb = x + ((size_t)b * CH + c0) * NPIX + n0;
    #pragma unroll
    for (int i = 0; i < 4; ++i) {
        const int c = g + 16 * i;
        const float4 v = *(const float4*)&xb[(size_t)c * NPIX + 4 * a];
        S[c][4*a+0] = v.x; S[c][4*a+1] = v.y; S[c][4*a+2] = v.z; S[c][4*a+3] = v.w;
    }
    __syncthreads();
    unsigned short* ob = XT + ((size_t)b * NPIX + n0) * CH + c0;
    #pragma unroll
    for (int i = 0; i < 4; ++i) {
        const int n = g + 16 * i;
        unsigned short b0 = f2bf_rne(S[4*a+0][n]);
        unsigned short b1 = f2bf_rne(S[4*a+1][n]);
        unsigned short b2 = f2bf_rne(S[4*a+2][n]);
        unsigned short b3 = f2bf_rne(S[4*a+3][n]);
        uint2 st;
        st.x = (unsigned int)b0 | ((unsigned int)b1 << 16);
        st.y = (unsigned int)b2 | ((unsigned int)b3 << 16);
        *(uint2*)&ob[(size_t)n * CH + 4 * a] = st;
    }
}

// ---------------------------------------------------------------------------
// QKV projection, MFMA, LDS-free mainloop (unchanged).
// ---------------------------------------------------------------------------
__global__ __launch_bounds__(256, 2) void qkv_proj(
    const unsigned short* __restrict__ XT, const unsigned short* __restrict__ Wb,
    const float* __restrict__ bq, const float* __restrict__ bk,
    const float* __restrict__ bv,
    unsigned short* __restrict__ QT, unsigned short* __restrict__ KT,
    unsigned short* __restrict__ V)
{
    __shared__ unsigned short OT[4][2048];
    const int t = threadIdx.x, w = t >> 6, l = t & 63;
    const int lo = l & 15, hi = l >> 4;
    const int b = blockIdx.z;
    const int o0 = blockIdx.y * 64 + (w >> 1) * 32;
    const int n0 = blockIdx.x * 128 + (w & 1) * 64;

    const unsigned short* Ab = Wb + (size_t)(o0 + lo) * CH + hi * 8;
    const unsigned short* Bb = XT + ((size_t)b * NPIX + n0 + lo) * CH + hi * 8;

    f32x4 acc[2][4] = {};
    #pragma unroll 4
    for (int k = 0; k < CH; k += 32) {
        bf16x8 af[2], bf[4];
        #pragma unroll
        for (int i = 0; i < 2; ++i) af[i] = *(const bf16x8*)(Ab + i * 8192 + k);
        #pragma unroll
        for (int j = 0; j < 4; ++j) bf[j] = *(const bf16x8*)(Bb + j * 8192 + k);
        #pragma unroll
        for (int i = 0; i < 2; ++i)
            #pragma unroll
            for (int j = 0; j < 4; ++j)
                acc[i][j] = __builtin_amdgcn_mfma_f32_16x16x32_bf16(af[i], bf[j], acc[i][j], 0, 0, 0);
    }

    float bias[2][4];
    #pragma unroll
    for (int i = 0; i < 2; ++i)
        #pragma unroll
        for (int r = 0; r < 4; ++r) {
            const int orow = o0 + i * 16 + hi * 4 + r;
            if (o0 < 128)      bias[i][r] = bq[orow] * QSC;
            else if (o0 < 256) bias[i][r] = bk[orow - 128];
            else               bias[i][r] = bv[orow - 256];
        }

    if (o0 < 256) {
        const bool isQ = (o0 < 128);
        const int hh = (o0 & 127) >> 5;
        #pragma unroll
        for (int i = 0; i < 2; ++i)
            #pragma unroll
            for (int j = 0; j < 4; ++j) {
                const int nl = j * 16 + lo;
                const int og = i * 4 + hi;
                unsigned short v0 = f2bf_rne(acc[i][j][0] + bias[i][0]);
                unsigned short v1 = f2bf_rne(acc[i][j][1] + bias[i][1]);
                unsigned short v2 = f2bf_rne(acc[i][j][2] + bias[i][2]);
                unsigned short v3 = f2bf_rne(acc[i][j][3] + bias[i][3]);
                uint2 st;
                st.x = (unsigned int)v0 | ((unsigned int)v1 << 16);
                st.y = (unsigned int)v2 | ((unsigned int)v3 << 16);
                *(uint2*)&OT[w][nl * 32 + ((og ^ (nl & 7)) << 2)] = st;
            }
        unsigned short* outp = (isQ ? QT : KT) + (size_t)(b * NH + hh) * NPIX * 32;
        #pragma unroll
        for (int it = 0; it < 4; ++it) {
            const int nl = (l >> 2) + 16 * it, seg = l & 3;
            const int g0 = (2 * seg) ^ (nl & 7);
            const int g1 = (2 * seg + 1) ^ (nl & 7);
            const uint2 p0 = *(uint2*)&OT[w][nl * 32 + g0 * 4];
            const uint2 p1 = *(uint2*)&OT[w][nl * 32 + g1 * 4];
            uint4 st; st.x = p0.x; st.y = p0.y; st.z = p1.x; st.w = p1.y;
            *(uint4*)&outp[(size_t)(n0 + nl) * 32 + seg * 8] = st;
        }
    } else {
        const int hh = (o0 - 256) >> 7;
        const int cb = (o0 - 256) & 127;
        unsigned short* vb = V + (size_t)(b * NH + hh) * 128 * NPIX;
        #pragma unroll
        for (int i = 0; i < 2; ++i)
            #pragma unroll
            for (int j = 0; j < 4; ++j)
                #pragma unroll
                for (int r = 0; r < 4; ++r) {
                    const int c = cb + i * 16 + hi * 4 + r;
                    const int n = n0 + j * 16 + lo;
                    vb[(size_t)c * NPIX + n] = f2bf_rne(acc[i][j][r] + bias[i][r]);
                }
    }
}

// ---------------------------------------------------------------------------
// Fused flash attention v6: 32x32 swapped-operand MFMA, register-resident P.
// Wave (ch, kv): 32 q-rows (block), 64 of 128 channels, 512 of 1024 m.
// S^T = mfma_32x32x16(K, Q): lane owns row n=lane&31 (16 m vals; partner
// lane+32 has the rest). Softmax: reg fmax tree + 1 shfl_xor(32); P packed
// to bf16 words, 8 shfl_xor(32) + cndmask assemble PV B-frags. PV: A=V rows
// (contiguous loads), B=P: output O[c][n] with n=lane&31 -> all softmax
// state lane-local. No LDS / barriers in main loop. kv-partials merged via
// LDS f32 exchange, cooperative coalesced epilogue.
// ---------------------------------------------------------------------------
__global__ __launch_bounds__(256, 3) void attn(
    const unsigned short* __restrict__ QT, const unsigned short* __restrict__ KT,
    const unsigned short* __restrict__ V,  const float* __restrict__ x,
    const float* __restrict__ gamma, float* __restrict__ out)
{
    __shared__ float Xof[8192];            // [ch][cb][reg16][lane] f32 partials (32 KB)
    __shared__ float mlM[64], mlL[64];     // [ch][n] donor max / sum
    __shared__ float Ot[128 * 33];         // [c][n] final tile (16.9 KB)

    const int t = threadIdx.x, w = t >> 6, l = t & 63;
    const int xl = l & 31;                 // n for softmax/P/of; c-offset for V loads
    const int h  = l >> 5;
    const int h8 = h * 8;
    const int kv = w & 1, ch = w >> 1;

    // XCD-grouped decode: u%8 = bh%8 -> per-XCD K/Q/V working set ~1.5 MB (L2)
    const int u = blockIdx.x;              // 0..1023
    const int xcd = u & 7;
    const int rr = u >> 3;                 // 0..127
    const int nt = rr & 31;                // 32 n-tiles of 32 rows
    const int bh = xcd | ((rr >> 5) << 3); // 0..31
    const int n0 = nt * 32;

    const unsigned short* Qb = QT + (size_t)bh * NPIX * 32;
    const unsigned short* Kb = KT + (size_t)bh * NPIX * 32;
    const unsigned short* Vb = V + ((size_t)bh * 128 + ch * 64) * NPIX;

    const bf16x8 qf0 = *(const bf16x8*)&Qb[(size_t)(n0 + xl) * 32 + h8];
    const bf16x8 qf1 = *(const bf16x8*)&Qb[(size_t)(n0 + xl) * 32 + 16 + h8];

    f32x16 of0 = {}; f32x16 of1 = {};
    float mrow = -INFINITY, lrow = 0.f;
    const bool hb = (h != 0);

    #pragma unroll 2
    for (int tix = 0; tix < 16; ++tix) {
        const int m0 = kv * 512 + tix * 32;
        // K frags (rows m) and V frags (rows c) — all contiguous 16B loads
        const bf16x8 kf0 = *(const bf16x8*)&Kb[(size_t)(m0 + xl) * 32 + h8];
        const bf16x8 kf1 = *(const bf16x8*)&Kb[(size_t)(m0 + xl) * 32 + 16 + h8];
        const bf16x8 va0 = *(const bf16x8*)&Vb[(size_t)xl * NPIX + m0 + h8];
        const bf16x8 va1 = *(const bf16x8*)&Vb[(size_t)xl * NPIX + m0 + 16 + h8];
        const bf16x8 vb0 = *(const bf16x8*)&Vb[(size_t)(32 + xl) * NPIX + m0 + h8];
        const bf16x8 vb1 = *(const bf16x8*)&Vb[(size_t)(32 + xl) * NPIX + m0 + 16 + h8];

        // S^T[m][n]: C col = n = lane&31, rows = (r&3)+8*(r>>2)+4h
        const f32x16 z16 = {};
        __builtin_amdgcn_s_setprio(1);
        f32x16 sa = __builtin_amdgcn_mfma_f32_32x32x16_bf16(kf0, qf0, z16, 0, 0, 0);
        sa = __builtin_amdgcn_mfma_f32_32x32x16_bf16(kf1, qf1, sa, 0, 0, 0);
        __builtin_amdgcn_s_setprio(0);

        // row max (16 local + partner)
        float mx01 = fmaxf(sa[0], sa[1]),   mx23 = fmaxf(sa[2], sa[3]);
        float mx45 = fmaxf(sa[4], sa[5]),   mx67 = fmaxf(sa[6], sa[7]);
        float mx89 = fmaxf(sa[8], sa[9]),   mxab = fmaxf(sa[10], sa[11]);
        float mxcd = fmaxf(sa[12], sa[13]), mxef = fmaxf(sa[14], sa[15]);
        float mx = fmaxf(fmaxf(fmaxf(mx01, mx23), fmaxf(mx45, mx67)),
                         fmaxf(fmaxf(mx89, mxab), fmaxf(mxcd, mxef)));
        mx = fmaxf(mx, __shfl_xor(mx, 32));

        // defer-max: rescale only when the running max grows by > 11.5 (log2)
        if (__any(mx > mrow + 11.5f)) {
            const float mnew = fmaxf(mrow, mx);
            const float fsc = __builtin_amdgcn_exp2f(mrow - mnew);
            mrow = mnew; lrow *= fsc;
            of0 *= fsc; of1 *= fsc;
        }

        float p[16];
        #pragma unroll
        for (int r = 0; r < 16; ++r) p[r] = __builtin_amdgcn_exp2f(sa[r] - mrow);
        float ps = (((p[0]+p[1])+(p[2]+p[3])) + ((p[4]+p[5])+(p[6]+p[7])))
                 + (((p[8]+p[9])+(p[10]+p[11])) + ((p[12]+p[13])+(p[14]+p[15])));
        ps += __shfl_xor(ps, 32);
        lrow += ps;

        // pack P to bf16 pair-words, swap halves, assemble B-frags (all regs)
        unsigned pw[8], qw[8];
        #pragma unroll
        for (int i = 0; i < 8; ++i) pw[i] = pack_bf2_trunc(p[2*i], p[2*i+1]);
        #pragma unroll
        for (int i = 0; i < 8; ++i) qw[i] = __shfl_xor(pw[i], 32);

        u32x4 f0v, f1v;
        f0v.x = hb ? qw[2] : pw[0];  f0v.y = hb ? qw[3] : pw[1];
        f0v.z = hb ? pw[2] : qw[0];  f0v.w = hb ? pw[3] : qw[1];
        f1v.x = hb ? qw[6] : pw[4];  f1v.y = hb ? qw[7] : pw[5];
        f1v.z = hb ? pw[6] : qw[4];  f1v.w = hb ? pw[7] : qw[5];
        const bf16x8 pf0 = __builtin_bit_cast(bf16x8, f0v);
        const bf16x8 pf1 = __builtin_bit_cast(bf16x8, f1v);

        // PV: O[c][n] += V[c][m] P[m][n]
        __builtin_amdgcn_s_setprio(1);
        of0 = __builtin_amdgcn_mfma_f32_32x32x16_bf16(va0, pf0, of0, 0, 0, 0);
        of0 = __builtin_amdgcn_mfma_f32_32x32x16_bf16(va1, pf1, of0, 0, 0, 0);
        of1 = __builtin_amdgcn_mfma_f32_32x32x16_bf16(vb0, pf0, of1, 0, 0, 0);
        of1 = __builtin_amdgcn_mfma_f32_32x32x16_bf16(vb1, pf1, of1, 0, 0, 0);
        __builtin_amdgcn_s_setprio(0);
    }

    // ---- kv merge through LDS ----
    if (kv == 1) {
        #pragma unroll
        for (int r = 0; r < 16; ++r) {
            Xof[((ch * 2 + 0) * 16 + r) * 64 + l] = of0[r];
            Xof[((ch * 2 + 1) * 16 + r) * 64 + l] = of1[r];
        }
        if (h == 0) { mlM[ch * 32 + xl] = mrow; mlL[ch * 32 + xl] = lrow; }
    }
    __syncthreads();

    if (kv == 0) {
        const float mB = mlM[ch * 32 + xl], lB = mlL[ch * 32 + xl];
        const float ms = fmaxf(mrow, mB);
        const float fA = __builtin_amdgcn_exp2f(mrow - ms);
        const float fB = __builtin_amdgcn_exp2f(mB - ms);
        const float inv = 1.0f / (lrow * fA + lB * fB);
        const float sA = fA * inv, sB = fB * inv;
        #pragma unroll
        for (int cb = 0; cb < 2; ++cb) {
            #pragma unroll
            for (int r = 0; r < 16; ++r) {
                const float own = cb ? of1[r] : of0[r];
                const float dn  = Xof[((ch * 2 + cb) * 16 + r) * 64 + l];
                const int   c   = ch * 64 + cb * 32 + (r & 3) + 8 * (r >> 2) + 4 * h;
                Ot[c * 33 + xl] = own * sA + dn * sB;
            }
        }
    }
    __syncthreads();

    // ---- cooperative coalesced store: out = gamma*o + x ----
    {
        const float g = gamma[0];
        const int b = bh >> 2, hd = bh & 3;
        const size_t base = ((size_t)b * CH + hd * 128) * NPIX + n0;
        #pragma unroll 4
        for (int it = 0; it < 16; ++it) {
            const int idx = it * 256 + t;
            const int c = idx >> 5, n = idx & 31;
            const size_t gi = base + (size_t)c * NPIX + n;
            out[gi] = fmaf(g, Ot[c * 33 + n], x[gi]);
        }
    }
}

// ---------------------------------------------------------------------------
extern "C" void kernel_launch(void* const* d_in, const int* in_sizes, int n_in,
                              void* d_out, int out_size, void* d_ws, size_t ws_size,
                              hipStream_t stream)
{
    const float* x     = (const float*)d_in[0];
    const float* Wq    = (const float*)d_in[1];
    const float* bq    = (const float*)d_in[2];
    const float* Wk    = (const float*)d_in[3];
    const float* bk    = (const float*)d_in[4];
    const float* Wv    = (const float*)d_in[5];
    const float* bv    = (const float*)d_in[6];
    const float* gamma = (const float*)d_in[7];
    float* out = (float*)d_out;

    char* ws = (char*)d_ws;
    unsigned short* XTp = (unsigned short*)(ws);             // 8 MB
    unsigned short* Wbp = (unsigned short*)(ws + 8388608);   // 768 KB
    unsigned short* QTp = (unsigned short*)(ws + 9175040);   // 2 MB
    unsigned short* KTp = (unsigned short*)(ws + 11272192);  // 2 MB
    unsigned short* Vp  = (unsigned short*)(ws + 13369344);  // 8 MB

    prep<<<dim3(16, 8, 9), 256, 0, stream>>>(x, Wq, Wk, Wv, XTp, Wbp);
    qkv_proj<<<dim3(8, 12, 8), 256, 0, stream>>>(XTp, Wbp, bq, bk, bv, QTp, KTp, Vp);
    attn<<<dim3(1024), 256, 0, stream>>>(QTp, KTp, Vp, x, gamma, out);
}